// Round 1
// baseline (430.950 us; speedup 1.0000x reference)
//
#include <hip/hip_runtime.h>

// Problem constants (B,N,T,D) = (8,256,64,512)
#define Bb 8
#define Nn 256
#define Tt 64
#define Dd 512
#define NT (Nn * Tt)   // 16384

// d_out layout (all float32, concatenated in return order):
//   new_x      : Bb*NT*Dd = 67,108,864
//   new_mask   : Bb*NT    = 131,072
//   doc_seq_len: Bb       = 8
//   new_tag    : Bb*NT    = 131,072
#define O_MASK (Bb * NT * Dd)
#define O_DOC  (O_MASK + Bb * NT)
#define O_TAG  (O_DOC + Bb)

// ws layout: int offsets[Bb][Nn+1]  then  int src[Bb][NT]
#define WS_OFF_INTS (Bb * (Nn + 1))   // 2056 ints

// ---------------------------------------------------------------------------
// Kernel 1: per-batch exclusive scan of length[] (Nn=256 elems, 1 block/batch)
// ---------------------------------------------------------------------------
__global__ __launch_bounds__(Nn) void scan_kernel(const int* __restrict__ length,
                                                  int* __restrict__ ws_off,
                                                  float* __restrict__ out_doc) {
    __shared__ int s[Nn];
    const int b = blockIdx.x;
    const int tid = threadIdx.x;
    const int v = length[b * Nn + tid];
    s[tid] = v;
    __syncthreads();
    // Hillis-Steele inclusive scan over 256 entries
    for (int off = 1; off < Nn; off <<= 1) {
        int t = 0;
        if (tid >= off) t = s[tid - off];
        __syncthreads();
        if (tid >= off) s[tid] += t;
        __syncthreads();
    }
    ws_off[b * (Nn + 1) + tid] = s[tid] - v;   // exclusive prefix
    if (tid == Nn - 1) {
        ws_off[b * (Nn + 1) + Nn] = s[Nn - 1]; // total = doc_seq_len
        out_doc[b] = (float)s[Nn - 1];
    }
}

// ---------------------------------------------------------------------------
// Kernel 2: build gather map src[b][j] via binary search over segment offsets;
// also writes new_mask and new_tag (as float).
// ---------------------------------------------------------------------------
__global__ __launch_bounds__(256) void map_kernel(const int* __restrict__ tags,
                                                  const int* __restrict__ ws_off,
                                                  int* __restrict__ ws_src,
                                                  float* __restrict__ out_mask,
                                                  float* __restrict__ out_tag) {
    __shared__ int off[Nn + 1];
    const int tid = threadIdx.x;
    const int b = blockIdx.x >> 6;                 // 64 blocks per batch
    const int j = ((blockIdx.x & 63) << 8) | tid;  // position in [0, NT)

    off[tid] = ws_off[b * (Nn + 1) + tid];
    if (tid == 0) off[Nn] = ws_off[b * (Nn + 1) + Nn];
    __syncthreads();

    const int doc = off[Nn];
    int   src = -1;
    float m = 0.0f, tg = 0.0f;  // PAD_TAG = 0
    if (j < doc) {
        int lo = 0, hi = Nn - 1;
        #pragma unroll
        for (int it = 0; it < 8; ++it) {           // 2^8 = 256 segments
            int mid = (lo + hi + 1) >> 1;
            if (off[mid] <= j) lo = mid; else hi = mid - 1;
        }
        src = lo * Tt + (j - off[lo]);
        m = 1.0f;
        tg = (float)tags[b * NT + src];
    }
    ws_src[b * NT + j]   = src;
    out_mask[b * NT + j] = m;
    out_tag[b * NT + j]  = tg;
}

// ---------------------------------------------------------------------------
// Kernel 3: new_x[b,j,:] = x_gcn[b, j/T, :] + (src>=0 ? x[b, src, :] : 0)
// float4 lanes; one thread per 16B.
// ---------------------------------------------------------------------------
__global__ __launch_bounds__(256) void add_kernel(const float4* __restrict__ x,
                                                  const float4* __restrict__ gcn,
                                                  const int* __restrict__ ws_src,
                                                  float4* __restrict__ out) {
    const int e4   = blockIdx.x * 256 + threadIdx.x;  // float4 index, < 2^24
    const int row  = e4 >> 7;          // / (Dd/4 = 128)
    const int c    = e4 & 127;
    const int b    = row >> 14;        // / NT
    const int j    = row & (NT - 1);
    const int node = j >> 6;           // / Tt

    float4 v = gcn[(b * Nn + node) * 128 + c];
    const int src = ws_src[row];
    if (src >= 0) {
        const float4 xv = x[((b << 14) + src) * 128 + c];
        v.x += xv.x; v.y += xv.y; v.z += xv.z; v.w += xv.w;
    }
    out[e4] = v;
}

extern "C" void kernel_launch(void* const* d_in, const int* in_sizes, int n_in,
                              void* d_out, int out_size, void* d_ws, size_t ws_size,
                              hipStream_t stream) {
    const float* x     = (const float*)d_in[0];  // (B,N,T,D)
    const float* x_gcn = (const float*)d_in[1];  // (B,N,D)
    // d_in[2] = mask — unused (mask is a prefix mask, fully determined by length)
    const int* length  = (const int*)d_in[3];    // (B,N)
    const int* tags    = (const int*)d_in[4];    // (B,N,T)

    float* out    = (float*)d_out;
    int*   ws_off = (int*)d_ws;
    int*   ws_src = ws_off + WS_OFF_INTS;

    scan_kernel<<<Bb, Nn, 0, stream>>>(length, ws_off, out + O_DOC);
    map_kernel<<<Bb * (NT / 256), 256, 0, stream>>>(tags, ws_off, ws_src,
                                                    out + O_MASK, out + O_TAG);
    add_kernel<<<(Bb * NT * (Dd / 4)) / 256, 256, 0, stream>>>(
        (const float4*)x, (const float4*)x_gcn, ws_src, (float4*)out);
}